// Round 8
// baseline (238.560 us; speedup 1.0000x reference)
//
#include <hip/hip_runtime.h>
#include <cstdint>

// Head attention: x[4,4096,1024] fp32, Wq/Wk/Wv[1024,64] fp32 -> out[4,4096,64] fp32.
// Round 17 = r16 resubmitted (round-7 bench died to container-acquisition infra
// failure before the kernel ran; no hang mechanism exists here: ticket pattern
// has no spin-wait, cnt re-zeroed in-stream each launch, device-scope atomics).
//  K3 fused into K2 via threadfence + atomic ticket: last of the 4 h-blocks
//  per (b,qt2) group combines, own partial from REGISTERS (f32), 3 sibling
//  partials from pbuf (L2-hot). One launch fewer.
//  K0: wt_prep  - W -> bf16 per-64k-step LDS-image slabs; Wq pre-scaled; cnt=0
//  K1: qkv_proj - 32-row blocks, BK=64, staggered slab phase, counted-vmcnt dbuf
//  K2: flash    - fat tile (b, qt2-128rows, h4), dbuf KV slab, in-reg P,
//                 fused ticket-combine epilogue

typedef __bf16 bf16;
typedef __bf16 bf16x4 __attribute__((ext_vector_type(4)));
typedef __bf16 bf16x8 __attribute__((ext_vector_type(8)));
typedef float  f32x4  __attribute__((ext_vector_type(4)));

#define MFMA16(a, b, c) __builtin_amdgcn_mfma_f32_16x16x32_bf16((a), (b), (c), 0, 0, 0)

#if __has_builtin(__builtin_amdgcn_exp2f)
#define EXP2(x) __builtin_amdgcn_exp2f(x)
#else
#define EXP2(x) exp2f(x)
#endif

#define B_SZ 4
#define T_SZ 4096
#define C_SZ 1024
#define H_SZ 64
#define M_SZ (B_SZ * T_SZ)
#define QSCALE (1.4426950408889634f / 32.0f)   // log2(e)/sqrt(1024)
#define P_O 8192                               // bf16 elems per O-partial (128x64)
#define P_L 128                                // f32 elems per l-partial

// async 16B global->LDS DMA; LDS dest is wave-uniform base + lane*16.
__device__ __forceinline__ void dma16(const void* g, void* l) {
    __builtin_amdgcn_global_load_lds(
        (const __attribute__((address_space(1))) uint32_t*)(uintptr_t)g,
        (__attribute__((address_space(3))) uint32_t*)(uint32_t)(uintptr_t)l,
        16, 0, 0);
}

// top-of-iter: counted wait (leave N newest loads in flight) + join barrier.
#define WAIT_BARRIER(N) do {                                       \
    asm volatile("s_waitcnt vmcnt(" #N ")" ::: "memory");          \
    __builtin_amdgcn_s_barrier();                                  \
    __builtin_amdgcn_sched_barrier(0);                             \
} while (0)

// bottom-of-iter: raw barrier (NO vmcnt drain -- prefetch stays in flight).
#define BOT_BARRIER() do {                                         \
    __builtin_amdgcn_sched_barrier(0);                             \
    __builtin_amdgcn_s_barrier();                                  \
    __builtin_amdgcn_sched_barrier(0);                             \
} while (0)

// -------------------------------------------------------------------------
// K0: wt2 image, per 64-k outer step s: elem off =
//   s*12288 + sub*6144 + quad*1536 + n*8 + j  (k = s*64+sub*32+quad*8+j, n = 0..191).
// Also zeroes the 128 group-ticket counters for this iteration.
// -------------------------------------------------------------------------
__global__ __launch_bounds__(256) void wt_prep(
    const float* __restrict__ Wq, const float* __restrict__ Wk,
    const float* __restrict__ Wv, bf16* __restrict__ wt2,
    int* __restrict__ cnt)
{
    const int n4 = blockIdx.x, t = threadIdx.x;
    if (n4 == 0 && t < 128) cnt[t] = 0;
    const int nbase = n4 * 4;
    const float* W = (nbase < 64) ? Wq : (nbase < 128 ? Wk : Wv);
    const float sc = (nbase < 64) ? QSCALE : 1.0f;
    const int ncol = nbase & 63;
    #pragma unroll
    for (int i = 0; i < 4; ++i) {
        const int k = i * 256 + t;
        const float4 v = *(const float4*)(W + (size_t)k * H_SZ + ncol);
        const float vals[4] = {v.x, v.y, v.z, v.w};
        const size_t base = (size_t)(k >> 6) * 12288 + (size_t)((k >> 5) & 1) * 6144
                          + (size_t)((k >> 3) & 3) * 1536 + (k & 7);
        #pragma unroll
        for (int m = 0; m < 4; ++m)
            wt2[base + (size_t)(nbase + m) * 8] = (bf16)(vals[m] * sc);
    }
}

// -------------------------------------------------------------------------
// K1: qkv. grid 512 x 256 (4 waves). Block = 32 rows x 192 fused cols.
// 16 steps of BK=64, slab phase staggered by block. Double-buffered slabs
// (x 8KB + W 24KB per buffer, 64KB total): per step issue next stage's 8
// DMAs, wait vmcnt(8) (= previous stage done, new in flight), barrier,
// compute, raw barrier. Tail step waits vmcnt(0).
// -------------------------------------------------------------------------
__global__ __launch_bounds__(256) void qkv_proj(
    const float* __restrict__ x, const bf16* __restrict__ wt2,
    bf16* __restrict__ qw, bf16* __restrict__ kw2, bf16* __restrict__ vtw2)
{
    const int m0 = blockIdx.x * 32;
    const int tid = threadIdx.x;
    const int wave = tid >> 6, lane = tid & 63;
    const int quad = lane >> 4, l15 = lane & 15;
    const int phase = blockIdx.x & 15;             // slab-phase stagger

    __shared__ __align__(16) float xs[2][2 * 4 * 32 * 8];   // 2 x 8 KB
    __shared__ __align__(16) bf16  ws[2][2 * 4 * 192 * 8];  // 2 x 24 KB

    f32x4 acc[2][3] = {};                          // [mg][ntile]

    // x DMA granule (per thread, i in {0,1}): sub=i, quad=(tid>>6)&3,
    // row=(tid>>1)&31, half=tid&1. k-offset within step: sub*128B+quad*32B+half*16B.
    const char* xg = (const char*)x
        + (size_t)(m0 + ((tid >> 1) & 31)) * 4096
        + (size_t)((tid >> 6) & 3) * 32 + (size_t)(tid & 1) * 16;
    const char* wg = (const char*)wt2 + (size_t)tid * 16;

    auto stage = [&](int s, int buf) {
        const size_t se = (size_t)((s + phase) & 15);
        char* xl = (char*)(&xs[buf][0]) + (size_t)tid * 16;
        char* wl = (char*)(&ws[buf][0]) + (size_t)tid * 16;
        dma16(xg + se * 256, xl);
        dma16(xg + se * 256 + 128, xl + 4096);
        #pragma unroll
        for (int i = 0; i < 6; ++i)
            dma16(wg + se * 24576 + (size_t)i * 4096, wl + (size_t)i * 4096);
    };

    stage(0, 0);

    for (int s = 0; s < 16; ++s) {
        if (s < 15) {
            stage(s + 1, (s + 1) & 1);             // 8 new DMAs in flight
            WAIT_BARRIER(8);                       // previous stage complete
        } else {
            WAIT_BARRIER(0);                       // tail: drain last stage
        }
        const float* xb = &xs[s & 1][0];
        const bf16*  wb = &ws[s & 1][0];

        #pragma unroll
        for (int ss = 0; ss < 2; ++ss) {
            bf16x8 a[2];
            #pragma unroll
            for (int mg = 0; mg < 2; ++mg) {
                const float* ap = xb + ss * 1024 + quad * 256 + (mg * 16 + l15) * 8;
                const f32x4 lo = *(const f32x4*)ap;
                const f32x4 hi = *(const f32x4*)(ap + 4);
                a[mg][0] = (bf16)lo[0]; a[mg][1] = (bf16)lo[1];
                a[mg][2] = (bf16)lo[2]; a[mg][3] = (bf16)lo[3];
                a[mg][4] = (bf16)hi[0]; a[mg][5] = (bf16)hi[1];
                a[mg][6] = (bf16)hi[2]; a[mg][7] = (bf16)hi[3];
            }
            #pragma unroll
            for (int i = 0; i < 3; ++i) {
                const int nt = wave * 3 + i;
                const bf16x8 wf = *(const bf16x8*)(wb + ss * 6144 + quad * 1536
                                                   + (nt * 16 + l15) * 8);
                #pragma unroll
                for (int mg = 0; mg < 2; ++mg)
                    acc[mg][i] = MFMA16(a[mg], wf, acc[mg][i]);
            }
        }

        BOT_BARRIER();   // reads of buf[s&1] done before it is re-staged
    }

    // epilogue: row t = m0+mg*16+quad*4+r, col n = (wave*3+i)*16+l15
    #pragma unroll
    for (int mg = 0; mg < 2; ++mg)
        #pragma unroll
        for (int i = 0; i < 3; ++i) {
            const int n = (wave * 3 + i) * 16 + l15;
            const int which = n >> 6, col = n & 63;
            #pragma unroll
            for (int r = 0; r < 4; ++r) {
                const int t = m0 + mg * 16 + quad * 4 + r;
                const bf16 v = (bf16)acc[mg][i][r];
                if (which == 0) {
                    qw[(size_t)t * H_SZ + col] = v;
                } else if (which == 1) {
                    // K slab: jt*4096 + ((col>>5)*4 + ((col>>3)&3))*512 + (t&63)*8 + (col&7)
                    kw2[(size_t)(t >> 6) * 4096
                        + (size_t)(((col >> 5) << 2) + ((col >> 3) & 3)) * 512
                        + (size_t)(t & 63) * 8 + (col & 7)] = v;
                } else {
                    // V slab, kv-permuted for in-register P:
                    // p = ((t6>>2)&3)*8 + (t6&3)*2 + ((t6>>4)&1) + (t6>>5)*32
                    const int t6 = t & 63;
                    const int p = ((t6 >> 2) & 3) * 8 + (t6 & 3) * 2
                                + ((t6 >> 4) & 1) + (t6 >> 5) * 32;
                    vtw2[(size_t)(t >> 6) * 4096
                         + (size_t)(p >> 3) * 512 + (size_t)col * 8 + (p & 7)] = v;
                }
            }
        }
}

// -------------------------------------------------------------------------
// K2: causal flash, fat tile, in-register P, fused combine. grid 512 x 256.
// Item (b, qt2 in 0..31, h in 0..3): 128 q-rows, 4 waves x 32 rows.
// QK swapped: s4t[ct][mg2] = MFMA16(K, Q) -> lane (quad,l15) holds
// P^T elems q = mg2*16+l15, kv = ct*16+quad*4+rr. With vtw2's kv-perm,
// pa[mg2][frag][j] = exp2(s4t[(j&1)+2*frag][mg2][j>>1]) -- no LDS for P.
// Double-buffered 16KB KV slab; counted vmcnt(4) wait.
// Epilogue: write partial (O bf16, l f32); threadfence + atomic ticket;
// the 4th block of the group combines (own partial from registers).
// -------------------------------------------------------------------------
__global__ __launch_bounds__(256) void flash_attn(
    const bf16* __restrict__ qw, const bf16* __restrict__ kw2,
    const bf16* __restrict__ vtw2, bf16* __restrict__ pbuf_o,
    float* __restrict__ pbuf_l, int* __restrict__ cnt,
    float* __restrict__ out)
{
    const int bx = blockIdx.x;
    const int item = (bx & 1) ? (511 - (bx >> 1)) : (bx >> 1);  // serpentine
    const int qt2 = 31 - (item >> 4);                           // heavy first
    const int b   = (item >> 2) & 3;
    const int h   = item & 3;
    const int i0  = qt2 * 128;
    const int nkv = qt2 * 2 + 2;     // kv tiles 0..2*qt2+1 cover the 128 q-rows

    const int tid = threadIdx.x;
    const int wave = tid >> 6, lane = tid & 63;
    const int quad = lane >> 4, l15 = lane & 15;

    __shared__ __align__(16) bf16 kvs[2][8192];      // 2 x 16 KB: K 8K | V 8K

    // Q frags (B-operand role): rows i0 + wave*32 + mg2*16 + l15, head quad*8 (+32)
    bf16x8 aq[2][2];
    #pragma unroll
    for (int mg2 = 0; mg2 < 2; ++mg2) {
        const bf16* qp = qw + ((size_t)b * T_SZ + i0 + wave * 32 + mg2 * 16 + l15) * H_SZ
                       + quad * 8;
        aq[mg2][0] = *(const bf16x8*)qp;
        aq[mg2][1] = *(const bf16x8*)(qp + 32);
    }
    const bf16 onev = (bf16)1.0f;
    const bf16x8 vone = {onev, onev, onev, onev, onev, onev, onev, onev};

    const char* kgb = (const char*)kw2 + (size_t)b * 524288;
    const char* vgb = (const char*)vtw2 + (size_t)b * 524288;

    f32x4 o[2][4] = {};
    f32x4 osum[2] = {};

    auto stage = [&](int jt, int buf) {
        const char* ks = kgb + (size_t)jt * 8192;
        const char* vs = vgb + (size_t)jt * 8192;
        char* dst = (char*)(&kvs[buf][0]) + (size_t)tid * 16;
        dma16(ks + (size_t)tid * 16, dst);
        dma16(ks + 4096 + (size_t)tid * 16, dst + 4096);
        dma16(vs + (size_t)tid * 16, dst + 8192);
        dma16(vs + 4096 + (size_t)tid * 16, dst + 12288);
    };

    if (h < nkv) stage(h, 0);

    int c = 0;
    for (int jt = h; jt < nkv; jt += 4, c ^= 1) {
        if (jt + 4 < nkv) {
            stage(jt + 4, c ^ 1);                  // 4 new DMAs in flight
            WAIT_BARRIER(4);                       // previous stage complete
        } else {
            WAIT_BARRIER(0);                       // tail: drain last stage
        }
        const bf16* kb = &kvs[c][0];
        const bf16* vb = &kvs[c][0] + 4096;

        // QK swapped: A = K-frag (rows = kv), B = Q-frag (cols = q).
        f32x4 s4t[4][2] = {};                      // [ct][mg2]
        __builtin_amdgcn_s_setprio(1);
        #pragma unroll
        for (int ct = 0; ct < 4; ++ct) {
            const bf16x8 k0 = *(const bf16x8*)(kb + (0 * 4 + quad) * 512 + (ct * 16 + l15) * 8);
            const bf16x8 k1 = *(const bf16x8*)(kb + (1 * 4 + quad) * 512 + (ct * 16 + l15) * 8);
            #pragma unroll
            for (int mg2 = 0; mg2 < 2; ++mg2) {
                s4t[ct][mg2] = MFMA16(k0, aq[mg2][0], s4t[ct][mg2]);
                s4t[ct][mg2] = MFMA16(k1, aq[mg2][1], s4t[ct][mg2]);
            }
        }
        __builtin_amdgcn_s_setprio(0);

        // causal mask (swapped layout): q = i0+wave*32+mg2*16+l15,
        // kv = jt*64 + ct*16 + quad*4 + rr; only top two kv tiles cross.
        if (jt >= 2 * qt2) {
            #pragma unroll
            for (int mg2 = 0; mg2 < 2; ++mg2) {
                const int gq = i0 + wave * 32 + mg2 * 16 + l15;
                #pragma unroll
                for (int ct = 0; ct < 4; ++ct) {
                    const int gkv0 = jt * 64 + ct * 16 + quad * 4;
                    #pragma unroll
                    for (int rr = 0; rr < 4; ++rr)
                        if (gkv0 + rr > gq) s4t[ct][mg2][rr] = -3.0e38f;
                }
            }
        }

        // P fragments entirely in-register (kv-perm matches vtw2):
        // pa[mg2][frag][j] = exp2(s4t[(j&1)+2*frag][mg2][j>>1])
        bf16x8 pa[2][2];
        #pragma unroll
        for (int mg2 = 0; mg2 < 2; ++mg2)
            #pragma unroll
            for (int j = 0; j < 8; ++j) {
                pa[mg2][0][j] = (bf16)EXP2(s4t[j & 1][mg2][j >> 1]);
                pa[mg2][1][j] = (bf16)EXP2(s4t[2 + (j & 1)][mg2][j >> 1]);
            }

        // PV: each V frag read once, used for both row-groups.
        __builtin_amdgcn_s_setprio(1);
        #pragma unroll
        for (int ht = 0; ht < 4; ++ht) {
            const bf16x8 v0 = *(const bf16x8*)(vb + (0 * 4 + quad) * 512 + (ht * 16 + l15) * 8);
            const bf16x8 v1 = *(const bf16x8*)(vb + (1 * 4 + quad) * 512 + (ht * 16 + l15) * 8);
            #pragma unroll
            for (int mg2 = 0; mg2 < 2; ++mg2) {
                o[mg2][ht] = MFMA16(pa[mg2][0], v0, o[mg2][ht]);
                o[mg2][ht] = MFMA16(pa[mg2][1], v1, o[mg2][ht]);
            }
        }
        #pragma unroll
        for (int mg2 = 0; mg2 < 2; ++mg2) {
            osum[mg2] = MFMA16(pa[mg2][0], vone, osum[mg2]);
            osum[mg2] = MFMA16(pa[mg2][1], vone, osum[mg2]);
        }
        __builtin_amdgcn_s_setprio(0);

        BOT_BARRIER();   // reads of kvs[c] done before it is re-staged
    }

    // ---- epilogue A: write own partial (siblings need it) ----
    const int grp = b * 32 + qt2;
    bf16* pb_o = pbuf_o + (size_t)(grp * 4 + h) * P_O;
    float* pb_l = pbuf_l + (size_t)(grp * 4 + h) * P_L;
    #pragma unroll
    for (int mg2 = 0; mg2 < 2; ++mg2) {
        const int L0 = wave * 32 + mg2 * 16 + quad * 4;
        #pragma unroll
        for (int ht = 0; ht < 4; ++ht)
            #pragma unroll
            for (int rr = 0; rr < 4; ++rr)
                pb_o[(L0 + rr) * 64 + ht * 16 + l15] = (bf16)o[mg2][ht][rr];
        if (l15 == 0) {
            #pragma unroll
            for (int rr = 0; rr < 4; ++rr)
                pb_l[L0 + rr] = osum[mg2][rr];
        }
    }

    // ---- epilogue B: ticket; 4th block of the group combines (K3 fused) ----
    __shared__ int last_flag;
    __threadfence();          // each thread: order its partial writes (release)
    __syncthreads();          // all threads' fences done before the ticket
    if (tid == 0) {
        const int t = __hip_atomic_fetch_add(&cnt[grp], 1, __ATOMIC_ACQ_REL,
                                             __HIP_MEMORY_SCOPE_AGENT);
        last_flag = (t == 3);
    }
    __syncthreads();
    if (!last_flag) return;
    __threadfence();          // acquire siblings' partial writes

    const bf16* gb_o = pbuf_o + (size_t)(grp * 4) * P_O;
    const float* gb_l = pbuf_l + (size_t)(grp * 4) * P_L;
    float* ob = out + ((size_t)b * T_SZ + i0) * H_SZ;
    #pragma unroll
    for (int mg2 = 0; mg2 < 2; ++mg2) {
        const int L0 = wave * 32 + mg2 * 16 + quad * 4;
        float inv[4];
        #pragma unroll
        for (int rr = 0; rr < 4; ++rr) {
            float ls = osum[mg2][rr];
            #pragma unroll
            for (int hh = 0; hh < 4; ++hh)
                if (hh != h) ls += gb_l[(size_t)hh * P_L + L0 + rr];
            inv[rr] = 1.0f / ls;
        }
        #pragma unroll
        for (int ht = 0; ht < 4; ++ht)
            #pragma unroll
            for (int rr = 0; rr < 4; ++rr) {
                float v = o[mg2][ht][rr];
                #pragma unroll
                for (int hh = 0; hh < 4; ++hh)
                    if (hh != h)
                        v += (float)gb_o[(size_t)hh * P_O + (L0 + rr) * 64 + ht * 16 + l15];
                ob[(size_t)(L0 + rr) * H_SZ + ht * 16 + l15] = v * inv[rr];
            }
    }
}

extern "C" void kernel_launch(void* const* d_in, const int* in_sizes, int n_in,
                              void* d_out, int out_size, void* d_ws, size_t ws_size,
                              hipStream_t stream) {
    const float* x  = (const float*)d_in[0];
    const float* Wq = (const float*)d_in[1];
    const float* Wk = (const float*)d_in[2];
    const float* Wv = (const float*)d_in[3];

    bf16* qw   = (bf16*)d_ws;                          // 2 MB, plain [t][h]
    bf16* kw2  = qw + (size_t)M_SZ * H_SZ;             // 2 MB, per-kv-tile slabs
    bf16* vtw2 = kw2 + (size_t)M_SZ * H_SZ;            // 2 MB, kv-permuted slabs
    bf16* wt2  = vtw2 + (size_t)M_SZ * H_SZ;           // 384 KB, per-step slabs
    bf16* pbuf_o = wt2 + 3 * 64 * 1024;                // 8 MB bf16 O partials
    float* pbuf_l = (float*)(pbuf_o + (size_t)512 * P_O);  // 256 KB l partials
    int* cnt = (int*)(pbuf_l + (size_t)512 * P_L);     // 128 group tickets
    float* out = (float*)d_out;

    wt_prep<<<48, 256, 0, stream>>>(Wq, Wk, Wv, wt2, cnt);
    qkv_proj<<<M_SZ / 32, 256, 0, stream>>>(x, wt2, qw, kw2, vtw2);
    flash_attn<<<512, 256, 0, stream>>>(qw, kw2, vtw2, pbuf_o, pbuf_l, cnt, out);
}

// Round 9
// 137.383 us; speedup vs baseline: 1.7365x; 1.7365x over previous
//
#include <hip/hip_runtime.h>
#include <cstdint>

// Head attention: x[4,4096,1024] fp32, Wq/Wk/Wv[1024,64] fp32 -> out[4,4096,64] fp32.
// Round 18: fusion REVERTED (r16's per-block device fences = serialized L2
// writeback storm on 8 XCDs; K2 36->133 us). Back to r15 4-kernel structure.
// NEW: K1 x-DMA made transaction-efficient: per-lane global src remapped so
// each wave-instr reads 4 rows x 256B contiguous (was 32 rows x 32B strided),
// LDS dest stays linear; chunk-level XOR swizzle (c ^= row&7) folded into the
// source mapping AND the frag-read addresses (conflict-free b128, verified).
//  K0: wt_prep  - W -> bf16 per-64k-step LDS-image slabs; Wq pre-scaled (frozen)
//  K1: qkv_proj - 32-row blocks, BK=64, counted-vmcnt dbuf, coalesced-x
//  K2: flash    - fat tile (b, qt2-128rows, h4), dbuf KV slab, in-reg P (r15)
//  K3: combine  - out = sum_h O_h / sum_h l_h over bf16 partials (r15)

typedef __bf16 bf16;
typedef __bf16 bf16x4 __attribute__((ext_vector_type(4)));
typedef __bf16 bf16x8 __attribute__((ext_vector_type(8)));
typedef float  f32x4  __attribute__((ext_vector_type(4)));

#define MFMA16(a, b, c) __builtin_amdgcn_mfma_f32_16x16x32_bf16((a), (b), (c), 0, 0, 0)

#if __has_builtin(__builtin_amdgcn_exp2f)
#define EXP2(x) __builtin_amdgcn_exp2f(x)
#else
#define EXP2(x) exp2f(x)
#endif

#define B_SZ 4
#define T_SZ 4096
#define C_SZ 1024
#define H_SZ 64
#define M_SZ (B_SZ * T_SZ)
#define QSCALE (1.4426950408889634f / 32.0f)   // log2(e)/sqrt(1024)
#define P_O 8192                               // bf16 elems per O-partial (128x64)
#define P_L 128                                // f32 elems per l-partial

// async 16B global->LDS DMA; LDS dest is wave-uniform base + lane*16.
__device__ __forceinline__ void dma16(const void* g, void* l) {
    __builtin_amdgcn_global_load_lds(
        (const __attribute__((address_space(1))) uint32_t*)(uintptr_t)g,
        (__attribute__((address_space(3))) uint32_t*)(uint32_t)(uintptr_t)l,
        16, 0, 0);
}

// top-of-iter: counted wait (leave N newest loads in flight) + join barrier.
#define WAIT_BARRIER(N) do {                                       \
    asm volatile("s_waitcnt vmcnt(" #N ")" ::: "memory");          \
    __builtin_amdgcn_s_barrier();                                  \
    __builtin_amdgcn_sched_barrier(0);                             \
} while (0)

// bottom-of-iter: raw barrier (NO vmcnt drain -- prefetch stays in flight).
#define BOT_BARRIER() do {                                         \
    __builtin_amdgcn_sched_barrier(0);                             \
    __builtin_amdgcn_s_barrier();                                  \
    __builtin_amdgcn_sched_barrier(0);                             \
} while (0)

// -------------------------------------------------------------------------
// K0: wt2 image, per 64-k outer step s: elem off =
//   s*12288 + sub*6144 + quad*1536 + n*8 + j  (k = s*64+sub*32+quad*8+j, n = 0..191).
// -------------------------------------------------------------------------
__global__ __launch_bounds__(256) void wt_prep(
    const float* __restrict__ Wq, const float* __restrict__ Wk,
    const float* __restrict__ Wv, bf16* __restrict__ wt2)
{
    const int n4 = blockIdx.x, t = threadIdx.x;
    const int nbase = n4 * 4;
    const float* W = (nbase < 64) ? Wq : (nbase < 128 ? Wk : Wv);
    const float sc = (nbase < 64) ? QSCALE : 1.0f;
    const int ncol = nbase & 63;
    #pragma unroll
    for (int i = 0; i < 4; ++i) {
        const int k = i * 256 + t;
        const float4 v = *(const float4*)(W + (size_t)k * H_SZ + ncol);
        const float vals[4] = {v.x, v.y, v.z, v.w};
        const size_t base = (size_t)(k >> 6) * 12288 + (size_t)((k >> 5) & 1) * 6144
                          + (size_t)((k >> 3) & 3) * 1536 + (k & 7);
        #pragma unroll
        for (int m = 0; m < 4; ++m)
            wt2[base + (size_t)(nbase + m) * 8] = (bf16)(vals[m] * sc);
    }
}

// -------------------------------------------------------------------------
// K1: qkv. grid 512 x 256 (4 waves). Block = 32 rows x 192 fused cols.
// 16 steps of BK=64, slab phase staggered by block. Double-buffered slabs
// (x 8KB + W 24KB per buffer, 64KB total); counted vmcnt(8) prefetch.
// x slab image: per step, logical (row r 0..31, chunk c 0..15 of 16B) stored
// at dest chunk d = r*16 + (c ^ (r&7)). DMA dest linear (d = tid, tid+256);
// per-lane SRC remapped so each wave-instr reads 4 rows x 256B contiguous.
// Frag reads apply the same XOR (involution) -> conflict-free b128.
// -------------------------------------------------------------------------
__global__ __launch_bounds__(256) void qkv_proj(
    const float* __restrict__ x, const bf16* __restrict__ wt2,
    bf16* __restrict__ qw, bf16* __restrict__ kw2, bf16* __restrict__ vtw2)
{
    const int m0 = blockIdx.x * 32;
    const int tid = threadIdx.x;
    const int wave = tid >> 6, lane = tid & 63;
    const int quad = lane >> 4, l15 = lane & 15;
    const int phase = blockIdx.x & 15;             // slab-phase stagger

    __shared__ __align__(16) float xs[2][2 * 4 * 32 * 8];   // 2 x 8 KB
    __shared__ __align__(16) bf16  ws[2][2 * 4 * 192 * 8];  // 2 x 24 KB

    f32x4 acc[2][3] = {};                          // [mg][ntile]

    // x DMA: thread covers dest chunks d0 = tid (rows 0..15) and d0+256
    // (rows 16..31). r0 = tid>>4, cc = tid&15, src chunk c = cc ^ (r0&7)
    // (same for both: (r0+16)&7 == r0&7). Src byte (per step se):
    // (m0 + r)*4096 + se*256 + c*16.
    const int r0 = tid >> 4;
    const int csrc = (tid & 15) ^ (r0 & 7);
    const char* xg0 = (const char*)x + (size_t)(m0 + r0) * 4096 + (size_t)csrc * 16;
    const char* xg1 = xg0 + 16 * 4096;
    const char* wg = (const char*)wt2 + (size_t)tid * 16;

    auto stage = [&](int s, int buf) {
        const size_t se = (size_t)((s + phase) & 15);
        char* xl = (char*)(&xs[buf][0]) + (size_t)tid * 16;
        char* wl = (char*)(&ws[buf][0]) + (size_t)tid * 16;
        dma16(xg0 + se * 256, xl);
        dma16(xg1 + se * 256, xl + 4096);
        #pragma unroll
        for (int i = 0; i < 6; ++i)
            dma16(wg + se * 24576 + (size_t)i * 4096, wl + (size_t)i * 4096);
    };

    stage(0, 0);

    for (int s = 0; s < 16; ++s) {
        if (s < 15) {
            stage(s + 1, (s + 1) & 1);             // 8 new DMAs in flight
            WAIT_BARRIER(8);                       // previous stage complete
        } else {
            WAIT_BARRIER(0);                       // tail: drain last stage
        }
        const float* xb = &xs[s & 1][0];
        const bf16*  wb = &ws[s & 1][0];

        #pragma unroll
        for (int ss = 0; ss < 2; ++ss) {
            bf16x8 a[2];
            const int cbase = ss * 8 + quad * 2;   // lo chunk; hi = cbase+1
            #pragma unroll
            for (int mg = 0; mg < 2; ++mg) {
                const int row = mg * 16 + l15;
                const int rx = row & 7;
                const float* xrow = xb + row * 64;
                const f32x4 lo = *(const f32x4*)(xrow + ((cbase ^ rx) << 2));
                const f32x4 hi = *(const f32x4*)(xrow + (((cbase + 1) ^ rx) << 2));
                a[mg][0] = (bf16)lo[0]; a[mg][1] = (bf16)lo[1];
                a[mg][2] = (bf16)lo[2]; a[mg][3] = (bf16)lo[3];
                a[mg][4] = (bf16)hi[0]; a[mg][5] = (bf16)hi[1];
                a[mg][6] = (bf16)hi[2]; a[mg][7] = (bf16)hi[3];
            }
            #pragma unroll
            for (int i = 0; i < 3; ++i) {
                const int nt = wave * 3 + i;
                const bf16x8 wf = *(const bf16x8*)(wb + ss * 6144 + quad * 1536
                                                   + (nt * 16 + l15) * 8);
                #pragma unroll
                for (int mg = 0; mg < 2; ++mg)
                    acc[mg][i] = MFMA16(a[mg], wf, acc[mg][i]);
            }
        }

        BOT_BARRIER();   // reads of buf[s&1] done before it is re-staged
    }

    // epilogue: row t = m0+mg*16+quad*4+r, col n = (wave*3+i)*16+l15
    #pragma unroll
    for (int mg = 0; mg < 2; ++mg)
        #pragma unroll
        for (int i = 0; i < 3; ++i) {
            const int n = (wave * 3 + i) * 16 + l15;
            const int which = n >> 6, col = n & 63;
            #pragma unroll
            for (int r = 0; r < 4; ++r) {
                const int t = m0 + mg * 16 + quad * 4 + r;
                const bf16 v = (bf16)acc[mg][i][r];
                if (which == 0) {
                    qw[(size_t)t * H_SZ + col] = v;
                } else if (which == 1) {
                    // K slab: jt*4096 + ((col>>5)*4 + ((col>>3)&3))*512 + (t&63)*8 + (col&7)
                    kw2[(size_t)(t >> 6) * 4096
                        + (size_t)(((col >> 5) << 2) + ((col >> 3) & 3)) * 512
                        + (size_t)(t & 63) * 8 + (col & 7)] = v;
                } else {
                    // V slab, kv-permuted for in-register P:
                    // p = ((t6>>2)&3)*8 + (t6&3)*2 + ((t6>>4)&1) + (t6>>5)*32
                    const int t6 = t & 63;
                    const int p = ((t6 >> 2) & 3) * 8 + (t6 & 3) * 2
                                + ((t6 >> 4) & 1) + (t6 >> 5) * 32;
                    vtw2[(size_t)(t >> 6) * 4096
                         + (size_t)(p >> 3) * 512 + (size_t)col * 8 + (p & 7)] = v;
                }
            }
        }
}

// -------------------------------------------------------------------------
// K2: causal flash, fat tile, in-register P (r15 exact). grid 512 x 256.
// Item (b, qt2 in 0..31, h in 0..3): 128 q-rows, 4 waves x 32 rows.
// QK swapped: s4t[ct][mg2] = MFMA16(K, Q); with vtw2's kv-perm,
// pa[mg2][frag][j] = exp2(s4t[(j&1)+2*frag][mg2][j>>1]) -- no LDS for P.
// Double-buffered 16KB KV slab; counted vmcnt(4) wait.
// Partials: O bf16 (128x64) -> pbuf_o, l f32 (128) -> pbuf_l.
// -------------------------------------------------------------------------
__global__ __launch_bounds__(256) void flash_attn(
    const bf16* __restrict__ qw, const bf16* __restrict__ kw2,
    const bf16* __restrict__ vtw2, bf16* __restrict__ pbuf_o,
    float* __restrict__ pbuf_l)
{
    const int bx = blockIdx.x;
    const int item = (bx & 1) ? (511 - (bx >> 1)) : (bx >> 1);  // serpentine
    const int qt2 = 31 - (item >> 4);                           // heavy first
    const int b   = (item >> 2) & 3;
    const int h   = item & 3;
    const int i0  = qt2 * 128;
    const int nkv = qt2 * 2 + 2;     // kv tiles 0..2*qt2+1 cover the 128 q-rows

    const int tid = threadIdx.x;
    const int wave = tid >> 6, lane = tid & 63;
    const int quad = lane >> 4, l15 = lane & 15;

    __shared__ __align__(16) bf16 kvs[2][8192];      // 2 x 16 KB: K 8K | V 8K

    // Q frags (B-operand role): rows i0 + wave*32 + mg2*16 + l15, head quad*8 (+32)
    bf16x8 aq[2][2];
    #pragma unroll
    for (int mg2 = 0; mg2 < 2; ++mg2) {
        const bf16* qp = qw + ((size_t)b * T_SZ + i0 + wave * 32 + mg2 * 16 + l15) * H_SZ
                       + quad * 8;
        aq[mg2][0] = *(const bf16x8*)qp;
        aq[mg2][1] = *(const bf16x8*)(qp + 32);
    }
    const bf16 onev = (bf16)1.0f;
    const bf16x8 vone = {onev, onev, onev, onev, onev, onev, onev, onev};

    const char* kgb = (const char*)kw2 + (size_t)b * 524288;
    const char* vgb = (const char*)vtw2 + (size_t)b * 524288;

    f32x4 o[2][4] = {};
    f32x4 osum[2] = {};

    auto stage = [&](int jt, int buf) {
        const char* ks = kgb + (size_t)jt * 8192;
        const char* vs = vgb + (size_t)jt * 8192;
        char* dst = (char*)(&kvs[buf][0]) + (size_t)tid * 16;
        dma16(ks + (size_t)tid * 16, dst);
        dma16(ks + 4096 + (size_t)tid * 16, dst + 4096);
        dma16(vs + (size_t)tid * 16, dst + 8192);
        dma16(vs + 4096 + (size_t)tid * 16, dst + 12288);
    };

    if (h < nkv) stage(h, 0);

    int c = 0;
    for (int jt = h; jt < nkv; jt += 4, c ^= 1) {
        if (jt + 4 < nkv) {
            stage(jt + 4, c ^ 1);                  // 4 new DMAs in flight
            WAIT_BARRIER(4);                       // previous stage complete
        } else {
            WAIT_BARRIER(0);                       // tail: drain last stage
        }
        const bf16* kb = &kvs[c][0];
        const bf16* vb = &kvs[c][0] + 4096;

        // QK swapped: A = K-frag (rows = kv), B = Q-frag (cols = q).
        f32x4 s4t[4][2] = {};                      // [ct][mg2]
        __builtin_amdgcn_s_setprio(1);
        #pragma unroll
        for (int ct = 0; ct < 4; ++ct) {
            const bf16x8 k0 = *(const bf16x8*)(kb + (0 * 4 + quad) * 512 + (ct * 16 + l15) * 8);
            const bf16x8 k1 = *(const bf16x8*)(kb + (1 * 4 + quad) * 512 + (ct * 16 + l15) * 8);
            #pragma unroll
            for (int mg2 = 0; mg2 < 2; ++mg2) {
                s4t[ct][mg2] = MFMA16(k0, aq[mg2][0], s4t[ct][mg2]);
                s4t[ct][mg2] = MFMA16(k1, aq[mg2][1], s4t[ct][mg2]);
            }
        }
        __builtin_amdgcn_s_setprio(0);

        // causal mask (swapped layout): q = i0+wave*32+mg2*16+l15,
        // kv = jt*64 + ct*16 + quad*4 + rr; only top two kv tiles cross.
        if (jt >= 2 * qt2) {
            #pragma unroll
            for (int mg2 = 0; mg2 < 2; ++mg2) {
                const int gq = i0 + wave * 32 + mg2 * 16 + l15;
                #pragma unroll
                for (int ct = 0; ct < 4; ++ct) {
                    const int gkv0 = jt * 64 + ct * 16 + quad * 4;
                    #pragma unroll
                    for (int rr = 0; rr < 4; ++rr)
                        if (gkv0 + rr > gq) s4t[ct][mg2][rr] = -3.0e38f;
                }
            }
        }

        // P fragments entirely in-register (kv-perm matches vtw2):
        // pa[mg2][frag][j] = exp2(s4t[(j&1)+2*frag][mg2][j>>1])
        bf16x8 pa[2][2];
        #pragma unroll
        for (int mg2 = 0; mg2 < 2; ++mg2)
            #pragma unroll
            for (int j = 0; j < 8; ++j) {
                pa[mg2][0][j] = (bf16)EXP2(s4t[j & 1][mg2][j >> 1]);
                pa[mg2][1][j] = (bf16)EXP2(s4t[2 + (j & 1)][mg2][j >> 1]);
            }

        // PV: each V frag read once, used for both row-groups.
        __builtin_amdgcn_s_setprio(1);
        #pragma unroll
        for (int ht = 0; ht < 4; ++ht) {
            const bf16x8 v0 = *(const bf16x8*)(vb + (0 * 4 + quad) * 512 + (ht * 16 + l15) * 8);
            const bf16x8 v1 = *(const bf16x8*)(vb + (1 * 4 + quad) * 512 + (ht * 16 + l15) * 8);
            #pragma unroll
            for (int mg2 = 0; mg2 < 2; ++mg2) {
                o[mg2][ht] = MFMA16(pa[mg2][0], v0, o[mg2][ht]);
                o[mg2][ht] = MFMA16(pa[mg2][1], v1, o[mg2][ht]);
            }
        }
        #pragma unroll
        for (int mg2 = 0; mg2 < 2; ++mg2) {
            osum[mg2] = MFMA16(pa[mg2][0], vone, osum[mg2]);
            osum[mg2] = MFMA16(pa[mg2][1], vone, osum[mg2]);
        }
        __builtin_amdgcn_s_setprio(0);

        BOT_BARRIER();   // reads of kvs[c] done before it is re-staged
    }

    // epilogue: partial O rows L = wave*32 + mg2*16 + quad*4 + rr (O as bf16)
    bf16* pb_o = pbuf_o + (size_t)(((b * 32 + qt2) * 4) + h) * P_O;
    float* pb_l = pbuf_l + (size_t)(((b * 32 + qt2) * 4) + h) * P_L;
    #pragma unroll
    for (int mg2 = 0; mg2 < 2; ++mg2) {
        const int L0 = wave * 32 + mg2 * 16 + quad * 4;
        #pragma unroll
        for (int ht = 0; ht < 4; ++ht)
            #pragma unroll
            for (int rr = 0; rr < 4; ++rr)
                pb_o[(L0 + rr) * 64 + ht * 16 + l15] = (bf16)o[mg2][ht][rr];
        if (l15 == 0) {
            #pragma unroll
            for (int rr = 0; rr < 4; ++rr)
                pb_l[L0 + rr] = osum[mg2][rr];
        }
    }
}

// -------------------------------------------------------------------------
// K3: combine (r15 exact). grid 256 x 256. out = sum_h O_h / sum_h l_h.
// Block = 64 rows of one (b,qt2) 128-row partial set (half = bx&1).
// -------------------------------------------------------------------------
__global__ __launch_bounds__(256) void combine(
    const bf16* __restrict__ pbuf_o, const float* __restrict__ pbuf_l,
    float* __restrict__ out)
{
    const int bq2 = blockIdx.x >> 1, tid = threadIdx.x;
    const int row = ((blockIdx.x & 1) << 6) + (tid >> 2);   // 0..127
    const int c0 = (tid & 3) * 16;

    float a[16] = {};
    float l = 0.f;
    #pragma unroll
    for (int h = 0; h < 4; ++h) {
        const bf16* ph = pbuf_o + (size_t)(bq2 * 4 + h) * P_O + row * 64 + c0;
        const bf16x8 v0 = *(const bf16x8*)ph;
        const bf16x8 v1 = *(const bf16x8*)(ph + 8);
        #pragma unroll
        for (int j = 0; j < 8; ++j) {
            a[j]     += (float)v0[j];
            a[8 + j] += (float)v1[j];
        }
        l += pbuf_l[(size_t)(bq2 * 4 + h) * P_L + row];
    }
    const float inv = 1.0f / l;
    float* op = out + ((size_t)bq2 * 128 + row) * 64 + c0;
    #pragma unroll
    for (int g = 0; g < 4; ++g) {
        f32x4 v = {a[g * 4], a[g * 4 + 1], a[g * 4 + 2], a[g * 4 + 3]};
        *(f32x4*)(op + g * 4) = v * inv;
    }
}

extern "C" void kernel_launch(void* const* d_in, const int* in_sizes, int n_in,
                              void* d_out, int out_size, void* d_ws, size_t ws_size,
                              hipStream_t stream) {
    const float* x  = (const float*)d_in[0];
    const float* Wq = (const float*)d_in[1];
    const float* Wk = (const float*)d_in[2];
    const float* Wv = (const float*)d_in[3];

    bf16* qw   = (bf16*)d_ws;                          // 2 MB, plain [t][h]
    bf16* kw2  = qw + (size_t)M_SZ * H_SZ;             // 2 MB, per-kv-tile slabs
    bf16* vtw2 = kw2 + (size_t)M_SZ * H_SZ;            // 2 MB, kv-permuted slabs
    bf16* wt2  = vtw2 + (size_t)M_SZ * H_SZ;           // 384 KB, per-step slabs
    bf16* pbuf_o = wt2 + 3 * 64 * 1024;                // 8 MB bf16 O partials
    float* pbuf_l = (float*)(pbuf_o + (size_t)512 * P_O);  // 256 KB l partials
    float* out = (float*)d_out;

    wt_prep<<<48, 256, 0, stream>>>(Wq, Wk, Wv, wt2);
    qkv_proj<<<M_SZ / 32, 256, 0, stream>>>(x, wt2, qw, kw2, vtw2);
    flash_attn<<<512, 256, 0, stream>>>(qw, kw2, vtw2, pbuf_o, pbuf_l);
    combine<<<256, 256, 0, stream>>>(pbuf_o, pbuf_l, out);
}

// Round 10
// 132.788 us; speedup vs baseline: 1.7965x; 1.0346x over previous
//
#include <hip/hip_runtime.h>
#include <cstdint>

// Head attention: x[4,4096,1024] fp32, Wq/Wk/Wv[1024,64] fp32 -> out[4,4096,64] fp32.
// Round 19 (on r18): K1 rebuilt as 64-row x 512-thread blocks (8 waves =
// 2 row-halves x 4 col-groups). W slab (24KB/step) now amortized over 64 rows
// -> total DMA staging 262->160 MB (-39%), per-row LDS reads -22%. Grid 256 =
// exactly 1 block/CU (zero tail). Per-wave inner code identical to r18.
//  K0: wt_prep  - W -> bf16 per-64k-step LDS-image slabs; Wq pre-scaled (frozen)
//  K1: qkv_proj - 64-row blocks, 512 thr, BK=64, counted-vmcnt(5) dbuf, coalesced-x
//  K2: flash    - fat tile (b, qt2-128rows, h4), dbuf KV slab, in-reg P (frozen)
//  K3: combine  - out = sum_h O_h / sum_h l_h over bf16 partials (frozen)

typedef __bf16 bf16;
typedef __bf16 bf16x4 __attribute__((ext_vector_type(4)));
typedef __bf16 bf16x8 __attribute__((ext_vector_type(8)));
typedef float  f32x4  __attribute__((ext_vector_type(4)));

#define MFMA16(a, b, c) __builtin_amdgcn_mfma_f32_16x16x32_bf16((a), (b), (c), 0, 0, 0)

#if __has_builtin(__builtin_amdgcn_exp2f)
#define EXP2(x) __builtin_amdgcn_exp2f(x)
#else
#define EXP2(x) exp2f(x)
#endif

#define B_SZ 4
#define T_SZ 4096
#define C_SZ 1024
#define H_SZ 64
#define M_SZ (B_SZ * T_SZ)
#define QSCALE (1.4426950408889634f / 32.0f)   // log2(e)/sqrt(1024)
#define P_O 8192                               // bf16 elems per O-partial (128x64)
#define P_L 128                                // f32 elems per l-partial

// async 16B global->LDS DMA; LDS dest is wave-uniform base + lane*16.
__device__ __forceinline__ void dma16(const void* g, void* l) {
    __builtin_amdgcn_global_load_lds(
        (const __attribute__((address_space(1))) uint32_t*)(uintptr_t)g,
        (__attribute__((address_space(3))) uint32_t*)(uint32_t)(uintptr_t)l,
        16, 0, 0);
}

// top-of-iter: counted wait (leave N newest loads in flight) + join barrier.
#define WAIT_BARRIER(N) do {                                       \
    asm volatile("s_waitcnt vmcnt(" #N ")" ::: "memory");          \
    __builtin_amdgcn_s_barrier();                                  \
    __builtin_amdgcn_sched_barrier(0);                             \
} while (0)

// bottom-of-iter: raw barrier (NO vmcnt drain -- prefetch stays in flight).
#define BOT_BARRIER() do {                                         \
    __builtin_amdgcn_sched_barrier(0);                             \
    __builtin_amdgcn_s_barrier();                                  \
    __builtin_amdgcn_sched_barrier(0);                             \
} while (0)

// -------------------------------------------------------------------------
// K0: wt2 image, per 64-k outer step s: elem off =
//   s*12288 + sub*6144 + quad*1536 + n*8 + j  (k = s*64+sub*32+quad*8+j, n = 0..191).
// -------------------------------------------------------------------------
__global__ __launch_bounds__(256) void wt_prep(
    const float* __restrict__ Wq, const float* __restrict__ Wk,
    const float* __restrict__ Wv, bf16* __restrict__ wt2)
{
    const int n4 = blockIdx.x, t = threadIdx.x;
    const int nbase = n4 * 4;
    const float* W = (nbase < 64) ? Wq : (nbase < 128 ? Wk : Wv);
    const float sc = (nbase < 64) ? QSCALE : 1.0f;
    const int ncol = nbase & 63;
    #pragma unroll
    for (int i = 0; i < 4; ++i) {
        const int k = i * 256 + t;
        const float4 v = *(const float4*)(W + (size_t)k * H_SZ + ncol);
        const float vals[4] = {v.x, v.y, v.z, v.w};
        const size_t base = (size_t)(k >> 6) * 12288 + (size_t)((k >> 5) & 1) * 6144
                          + (size_t)((k >> 3) & 3) * 1536 + (k & 7);
        #pragma unroll
        for (int m = 0; m < 4; ++m)
            wt2[base + (size_t)(nbase + m) * 8] = (bf16)(vals[m] * sc);
    }
}

// -------------------------------------------------------------------------
// K1: qkv. grid 256 x 512 (8 waves: rh = wave>>2 row-half, cg = wave&3 col
// group). Block = 64 rows x 192 fused cols. 16 steps of BK=64, slab phase
// staggered by block. Double-buffered slabs (x 16KB + W 24KB per buffer,
// 80KB LDS): per step issue next stage's 5 DMAs/thread, wait vmcnt(5),
// barrier, compute, raw barrier. Tail waits vmcnt(0).
// x slab image per step: [row64][16 chunks], dest chunk d = r*16+(c^(r&7));
// DMA dest linear (d = tid, tid+512), per-lane SRC remapped -> each
// wave-instr reads 4 rows x 256B contiguous. Frag reads apply same XOR.
// -------------------------------------------------------------------------
__global__ __launch_bounds__(512) void qkv_proj(
    const float* __restrict__ x, const bf16* __restrict__ wt2,
    bf16* __restrict__ qw, bf16* __restrict__ kw2, bf16* __restrict__ vtw2)
{
    const int m0 = blockIdx.x * 64;
    const int tid = threadIdx.x;
    const int wave = tid >> 6, lane = tid & 63;
    const int quad = lane >> 4, l15 = lane & 15;
    const int rh = wave >> 2;                      // row-half 0/1
    const int cg = wave & 3;                       // col group 0..3
    const int phase = blockIdx.x & 15;             // slab-phase stagger

    __shared__ __align__(16) float xs[2][64 * 64];        // 2 x 16 KB
    __shared__ __align__(16) bf16  ws[2][2 * 4 * 192 * 8];// 2 x 24 KB

    f32x4 acc[2][3] = {};                          // [mg][ntile]

    // x DMA: thread covers dest chunks d = tid (rows 0..31) and tid+512
    // (rows 32..63). r0 = tid>>4, cc = tid&15, src chunk c = cc ^ (r0&7)
    // ((r0+32)&7 == r0&7). Src byte (per step se): (m0+r)*4096 + se*256 + c*16.
    const int r0 = tid >> 4;
    const int csrc = (tid & 15) ^ (r0 & 7);
    const char* xg0 = (const char*)x + (size_t)(m0 + r0) * 4096 + (size_t)csrc * 16;
    const char* xg1 = xg0 + (size_t)32 * 4096;
    const char* wg = (const char*)wt2 + (size_t)tid * 16;

    auto stage = [&](int s, int buf) {
        const size_t se = (size_t)((s + phase) & 15);
        char* xl = (char*)(&xs[buf][0]) + (size_t)tid * 16;
        char* wl = (char*)(&ws[buf][0]) + (size_t)tid * 16;
        dma16(xg0 + se * 256, xl);
        dma16(xg1 + se * 256, xl + 8192);
        #pragma unroll
        for (int i = 0; i < 3; ++i)
            dma16(wg + se * 24576 + (size_t)i * 8192, wl + (size_t)i * 8192);
    };

    stage(0, 0);

    for (int s = 0; s < 16; ++s) {
        if (s < 15) {
            stage(s + 1, (s + 1) & 1);             // 5 new DMAs in flight
            WAIT_BARRIER(5);                       // previous stage complete
        } else {
            WAIT_BARRIER(0);                       // tail: drain last stage
        }
        const float* xb = &xs[s & 1][0];
        const bf16*  wb = &ws[s & 1][0];

        #pragma unroll
        for (int ss = 0; ss < 2; ++ss) {
            bf16x8 a[2];
            const int cbase = ss * 8 + quad * 2;   // lo chunk; hi = cbase+1
            #pragma unroll
            for (int mg = 0; mg < 2; ++mg) {
                const int row = rh * 32 + mg * 16 + l15;
                const int rx = row & 7;
                const float* xrow = xb + row * 64;
                const f32x4 lo = *(const f32x4*)(xrow + ((cbase ^ rx) << 2));
                const f32x4 hi = *(const f32x4*)(xrow + (((cbase + 1) ^ rx) << 2));
                a[mg][0] = (bf16)lo[0]; a[mg][1] = (bf16)lo[1];
                a[mg][2] = (bf16)lo[2]; a[mg][3] = (bf16)lo[3];
                a[mg][4] = (bf16)hi[0]; a[mg][5] = (bf16)hi[1];
                a[mg][6] = (bf16)hi[2]; a[mg][7] = (bf16)hi[3];
            }
            #pragma unroll
            for (int i = 0; i < 3; ++i) {
                const int nt = cg * 3 + i;
                const bf16x8 wf = *(const bf16x8*)(wb + ss * 6144 + quad * 1536
                                                   + (nt * 16 + l15) * 8);
                #pragma unroll
                for (int mg = 0; mg < 2; ++mg)
                    acc[mg][i] = MFMA16(a[mg], wf, acc[mg][i]);
            }
        }

        BOT_BARRIER();   // reads of buf[s&1] done before it is re-staged
    }

    // epilogue: row t = m0+rh*32+mg*16+quad*4+r, col n = (cg*3+i)*16+l15
    #pragma unroll
    for (int mg = 0; mg < 2; ++mg)
        #pragma unroll
        for (int i = 0; i < 3; ++i) {
            const int n = (cg * 3 + i) * 16 + l15;
            const int which = n >> 6, col = n & 63;
            #pragma unroll
            for (int r = 0; r < 4; ++r) {
                const int t = m0 + rh * 32 + mg * 16 + quad * 4 + r;
                const bf16 v = (bf16)acc[mg][i][r];
                if (which == 0) {
                    qw[(size_t)t * H_SZ + col] = v;
                } else if (which == 1) {
                    // K slab: jt*4096 + ((col>>5)*4 + ((col>>3)&3))*512 + (t&63)*8 + (col&7)
                    kw2[(size_t)(t >> 6) * 4096
                        + (size_t)(((col >> 5) << 2) + ((col >> 3) & 3)) * 512
                        + (size_t)(t & 63) * 8 + (col & 7)] = v;
                } else {
                    // V slab, kv-permuted for in-register P:
                    // p = ((t6>>2)&3)*8 + (t6&3)*2 + ((t6>>4)&1) + (t6>>5)*32
                    const int t6 = t & 63;
                    const int p = ((t6 >> 2) & 3) * 8 + (t6 & 3) * 2
                                + ((t6 >> 4) & 1) + (t6 >> 5) * 32;
                    vtw2[(size_t)(t >> 6) * 4096
                         + (size_t)(p >> 3) * 512 + (size_t)col * 8 + (p & 7)] = v;
                }
            }
        }
}

// -------------------------------------------------------------------------
// K2: causal flash, fat tile, in-register P (r15 exact). grid 512 x 256.
// Item (b, qt2 in 0..31, h in 0..3): 128 q-rows, 4 waves x 32 rows.
// QK swapped: s4t[ct][mg2] = MFMA16(K, Q); with vtw2's kv-perm,
// pa[mg2][frag][j] = exp2(s4t[(j&1)+2*frag][mg2][j>>1]) -- no LDS for P.
// Double-buffered 16KB KV slab; counted vmcnt(4) wait.
// Partials: O bf16 (128x64) -> pbuf_o, l f32 (128) -> pbuf_l.
// -------------------------------------------------------------------------
__global__ __launch_bounds__(256) void flash_attn(
    const bf16* __restrict__ qw, const bf16* __restrict__ kw2,
    const bf16* __restrict__ vtw2, bf16* __restrict__ pbuf_o,
    float* __restrict__ pbuf_l)
{
    const int bx = blockIdx.x;
    const int item = (bx & 1) ? (511 - (bx >> 1)) : (bx >> 1);  // serpentine
    const int qt2 = 31 - (item >> 4);                           // heavy first
    const int b   = (item >> 2) & 3;
    const int h   = item & 3;
    const int i0  = qt2 * 128;
    const int nkv = qt2 * 2 + 2;     // kv tiles 0..2*qt2+1 cover the 128 q-rows

    const int tid = threadIdx.x;
    const int wave = tid >> 6, lane = tid & 63;
    const int quad = lane >> 4, l15 = lane & 15;

    __shared__ __align__(16) bf16 kvs[2][8192];      // 2 x 16 KB: K 8K | V 8K

    // Q frags (B-operand role): rows i0 + wave*32 + mg2*16 + l15, head quad*8 (+32)
    bf16x8 aq[2][2];
    #pragma unroll
    for (int mg2 = 0; mg2 < 2; ++mg2) {
        const bf16* qp = qw + ((size_t)b * T_SZ + i0 + wave * 32 + mg2 * 16 + l15) * H_SZ
                       + quad * 8;
        aq[mg2][0] = *(const bf16x8*)qp;
        aq[mg2][1] = *(const bf16x8*)(qp + 32);
    }
    const bf16 onev = (bf16)1.0f;
    const bf16x8 vone = {onev, onev, onev, onev, onev, onev, onev, onev};

    const char* kgb = (const char*)kw2 + (size_t)b * 524288;
    const char* vgb = (const char*)vtw2 + (size_t)b * 524288;

    f32x4 o[2][4] = {};
    f32x4 osum[2] = {};

    auto stage = [&](int jt, int buf) {
        const char* ks = kgb + (size_t)jt * 8192;
        const char* vs = vgb + (size_t)jt * 8192;
        char* dst = (char*)(&kvs[buf][0]) + (size_t)tid * 16;
        dma16(ks + (size_t)tid * 16, dst);
        dma16(ks + 4096 + (size_t)tid * 16, dst + 4096);
        dma16(vs + (size_t)tid * 16, dst + 8192);
        dma16(vs + 4096 + (size_t)tid * 16, dst + 12288);
    };

    if (h < nkv) stage(h, 0);

    int c = 0;
    for (int jt = h; jt < nkv; jt += 4, c ^= 1) {
        if (jt + 4 < nkv) {
            stage(jt + 4, c ^ 1);                  // 4 new DMAs in flight
            WAIT_BARRIER(4);                       // previous stage complete
        } else {
            WAIT_BARRIER(0);                       // tail: drain last stage
        }
        const bf16* kb = &kvs[c][0];
        const bf16* vb = &kvs[c][0] + 4096;

        // QK swapped: A = K-frag (rows = kv), B = Q-frag (cols = q).
        f32x4 s4t[4][2] = {};                      // [ct][mg2]
        __builtin_amdgcn_s_setprio(1);
        #pragma unroll
        for (int ct = 0; ct < 4; ++ct) {
            const bf16x8 k0 = *(const bf16x8*)(kb + (0 * 4 + quad) * 512 + (ct * 16 + l15) * 8);
            const bf16x8 k1 = *(const bf16x8*)(kb + (1 * 4 + quad) * 512 + (ct * 16 + l15) * 8);
            #pragma unroll
            for (int mg2 = 0; mg2 < 2; ++mg2) {
                s4t[ct][mg2] = MFMA16(k0, aq[mg2][0], s4t[ct][mg2]);
                s4t[ct][mg2] = MFMA16(k1, aq[mg2][1], s4t[ct][mg2]);
            }
        }
        __builtin_amdgcn_s_setprio(0);

        // causal mask (swapped layout): q = i0+wave*32+mg2*16+l15,
        // kv = jt*64 + ct*16 + quad*4 + rr; only top two kv tiles cross.
        if (jt >= 2 * qt2) {
            #pragma unroll
            for (int mg2 = 0; mg2 < 2; ++mg2) {
                const int gq = i0 + wave * 32 + mg2 * 16 + l15;
                #pragma unroll
                for (int ct = 0; ct < 4; ++ct) {
                    const int gkv0 = jt * 64 + ct * 16 + quad * 4;
                    #pragma unroll
                    for (int rr = 0; rr < 4; ++rr)
                        if (gkv0 + rr > gq) s4t[ct][mg2][rr] = -3.0e38f;
                }
            }
        }

        // P fragments entirely in-register (kv-perm matches vtw2):
        // pa[mg2][frag][j] = exp2(s4t[(j&1)+2*frag][mg2][j>>1])
        bf16x8 pa[2][2];
        #pragma unroll
        for (int mg2 = 0; mg2 < 2; ++mg2)
            #pragma unroll
            for (int j = 0; j < 8; ++j) {
                pa[mg2][0][j] = (bf16)EXP2(s4t[j & 1][mg2][j >> 1]);
                pa[mg2][1][j] = (bf16)EXP2(s4t[2 + (j & 1)][mg2][j >> 1]);
            }

        // PV: each V frag read once, used for both row-groups.
        __builtin_amdgcn_s_setprio(1);
        #pragma unroll
        for (int ht = 0; ht < 4; ++ht) {
            const bf16x8 v0 = *(const bf16x8*)(vb + (0 * 4 + quad) * 512 + (ht * 16 + l15) * 8);
            const bf16x8 v1 = *(const bf16x8*)(vb + (1 * 4 + quad) * 512 + (ht * 16 + l15) * 8);
            #pragma unroll
            for (int mg2 = 0; mg2 < 2; ++mg2) {
                o[mg2][ht] = MFMA16(pa[mg2][0], v0, o[mg2][ht]);
                o[mg2][ht] = MFMA16(pa[mg2][1], v1, o[mg2][ht]);
            }
        }
        #pragma unroll
        for (int mg2 = 0; mg2 < 2; ++mg2) {
            osum[mg2] = MFMA16(pa[mg2][0], vone, osum[mg2]);
            osum[mg2] = MFMA16(pa[mg2][1], vone, osum[mg2]);
        }
        __builtin_amdgcn_s_setprio(0);

        BOT_BARRIER();   // reads of kvs[c] done before it is re-staged
    }

    // epilogue: partial O rows L = wave*32 + mg2*16 + quad*4 + rr (O as bf16)
    bf16* pb_o = pbuf_o + (size_t)(((b * 32 + qt2) * 4) + h) * P_O;
    float* pb_l = pbuf_l + (size_t)(((b * 32 + qt2) * 4) + h) * P_L;
    #pragma unroll
    for (int mg2 = 0; mg2 < 2; ++mg2) {
        const int L0 = wave * 32 + mg2 * 16 + quad * 4;
        #pragma unroll
        for (int ht = 0; ht < 4; ++ht)
            #pragma unroll
            for (int rr = 0; rr < 4; ++rr)
                pb_o[(L0 + rr) * 64 + ht * 16 + l15] = (bf16)o[mg2][ht][rr];
        if (l15 == 0) {
            #pragma unroll
            for (int rr = 0; rr < 4; ++rr)
                pb_l[L0 + rr] = osum[mg2][rr];
        }
    }
}

// -------------------------------------------------------------------------
// K3: combine (r15 exact). grid 256 x 256. out = sum_h O_h / sum_h l_h.
// Block = 64 rows of one (b,qt2) 128-row partial set (half = bx&1).
// -------------------------------------------------------------------------
__global__ __launch_bounds__(256) void combine(
    const bf16* __restrict__ pbuf_o, const float* __restrict__ pbuf_l,
    float* __restrict__ out)
{
    const int bq2 = blockIdx.x >> 1, tid = threadIdx.x;
    const int row = ((blockIdx.x & 1) << 6) + (tid >> 2);   // 0..127
    const int c0 = (tid & 3) * 16;

    float a[16] = {};
    float l = 0.f;
    #pragma unroll
    for (int h = 0; h < 4; ++h) {
        const bf16* ph = pbuf_o + (size_t)(bq2 * 4 + h) * P_O + row * 64 + c0;
        const bf16x8 v0 = *(const bf16x8*)ph;
        const bf16x8 v1 = *(const bf16x8*)(ph + 8);
        #pragma unroll
        for (int j = 0; j < 8; ++j) {
            a[j]     += (float)v0[j];
            a[8 + j] += (float)v1[j];
        }
        l += pbuf_l[(size_t)(bq2 * 4 + h) * P_L + row];
    }
    const float inv = 1.0f / l;
    float* op = out + ((size_t)bq2 * 128 + row) * 64 + c0;
    #pragma unroll
    for (int g = 0; g < 4; ++g) {
        f32x4 v = {a[g * 4], a[g * 4 + 1], a[g * 4 + 2], a[g * 4 + 3]};
        *(f32x4*)(op + g * 4) = v * inv;
    }
}

extern "C" void kernel_launch(void* const* d_in, const int* in_sizes, int n_in,
                              void* d_out, int out_size, void* d_ws, size_t ws_size,
                              hipStream_t stream) {
    const float* x  = (const float*)d_in[0];
    const float* Wq = (const float*)d_in[1];
    const float* Wk = (const float*)d_in[2];
    const float* Wv = (const float*)d_in[3];

    bf16* qw   = (bf16*)d_ws;                          // 2 MB, plain [t][h]
    bf16* kw2  = qw + (size_t)M_SZ * H_SZ;             // 2 MB, per-kv-tile slabs
    bf16* vtw2 = kw2 + (size_t)M_SZ * H_SZ;            // 2 MB, kv-permuted slabs
    bf16* wt2  = vtw2 + (size_t)M_SZ * H_SZ;           // 384 KB, per-step slabs
    bf16* pbuf_o = wt2 + 3 * 64 * 1024;                // 8 MB bf16 O partials
    float* pbuf_l = (float*)(pbuf_o + (size_t)512 * P_O);  // 256 KB l partials
    float* out = (float*)d_out;

    wt_prep<<<48, 256, 0, stream>>>(Wq, Wk, Wv, wt2);
    qkv_proj<<<M_SZ / 64, 512, 0, stream>>>(x, wt2, qw, kw2, vtw2);
    flash_attn<<<512, 256, 0, stream>>>(qw, kw2, vtw2, pbuf_o, pbuf_l);
    combine<<<256, 256, 0, stream>>>(pbuf_o, pbuf_l, out);
}